// Round 5
// baseline (293.169 us; speedup 1.0000x reference)
//
#include <hip/hip_runtime.h>
#include <stdint.h>

// B=131072 rows, K=IN=256, N=OUT=256.
// temp = act @ weight.T (exact int32, |t| < 2^23); r = max|temp|;
// bw = ceil(log2(max(r,1))) (0 if r<=1); shift = bw-7;
// shift>0 ? round_shift(temp,shift) clipped to [-127,127] : int8-wrap(temp)
// exp_out = exp_in + weight_exp + max(shift,0)  (int16 semantics)
// Harness reads d_out as INT32: [B*N values, 1 exp scalar].
//
// v6: barrier-free pass 1.
//  - v2/v5 post-mortem: 2-barriers-per-K-step + compiler's vmcnt(0) drain
//    before every s_barrier is the limiter (dur identical at BM=64/128,
//    MfmaUtil ~7%, occupancy <=25%). K=256 needs NO K-pipeline: B is 128 KB.
//  - Full B staged in padded LDS ONCE (135 KB, 1 block/CU), single barrier.
//  - A: global->reg direct (wave-private rows; no LDS, no barriers).
//  - 1024 thr = 16 waves (4x4), acc[4][4]/wave (the PROVEN non-spill shape;
//    v3/v4's acc[16] spilled). Live set ~110 < 128 cap of (1024,4).
//  - grid 512 = 2 exact rounds over 256 CUs.
// pass 2 unchanged: in-place elementwise quantize (raw temp LLC-resident).

#define M_ROWS 131072
#define NK 256
#define BM 256       // block tile rows (4 row-waves x 64)
#define BST 264      // padded LDS row stride (bf16 elems) = 528 B

typedef __attribute__((ext_vector_type(8))) short bf16x8;
typedef __attribute__((ext_vector_type(4))) float f32x4;
typedef __attribute__((ext_vector_type(4))) float fv4;
typedef __attribute__((ext_vector_type(4))) int iv4;
typedef __attribute__((ext_vector_type(4))) unsigned int u32x4;
typedef __attribute__((ext_vector_type(4))) unsigned short us4;

__device__ __forceinline__ uint32_t pack_bf16(float a, float b) {
  // bf16(a) low half, bf16(b) high half; exact for integer-valued |v|<=255
  return __builtin_amdgcn_perm(__float_as_uint(b), __float_as_uint(a),
                               0x07060302u);
}

// Prepass: weight fp32 -> bf16 (65536 elems; L2/LLC-resident, 128 KB).
// Also zero-inits gmax (replaces a separate memset dispatch).
__global__ void wconv(const float* __restrict__ w, unsigned short* __restrict__ wb,
                      int* __restrict__ gmax) {
  if (blockIdx.x == 0 && threadIdx.x == 0) *gmax = 0;
  const int i = blockIdx.x * 256 + threadIdx.x;
  const fv4 f = ((const fv4*)w)[i];
  us4 o;
  o.x = (unsigned short)(__float_as_uint(f.x) >> 16);
  o.y = (unsigned short)(__float_as_uint(f.y) >> 16);
  o.z = (unsigned short)(__float_as_uint(f.z) >> 16);
  o.w = (unsigned short)(__float_as_uint(f.w) >> 16);
  ((us4*)wb)[i] = o;
}

// pass 1: barrier-free GEMM -> raw int32 store + global abs-max.
// 1024 threads = 16 waves in a 4x4 grid; wave (wr,wc) owns rows wr*64..+63,
// cols wc*64..+63 of the 256x256 block tile; acc[4][4] per wave.
__global__ __launch_bounds__(1024, 4) void gemm_maxstore(
    const float* __restrict__ act, const unsigned short* __restrict__ wgtb,
    int* __restrict__ out, int* __restrict__ gmax)
{
  __shared__ __align__(16) short Bs[NK * BST];   // 135168 B -> 1 block/CU
  __shared__ int smax;
  const int tid = threadIdx.x;
  if (tid == 0) smax = 0;

  // Stage full B once: wgtb row-major [col][k] bf16 -> padded LDS rows.
  for (int c = tid; c < NK * NK / 8; c += 1024) {   // 8 iters/thread
    const int col = c >> 5;            // 32 x u32x4 (16B) chunks per row
    const int k8  = (c & 31) << 3;
    *(u32x4*)&Bs[col * BST + k8] = ((const u32x4*)wgtb)[c];
  }
  __syncthreads();   // the only barrier before the epilogue

  const int lane = tid & 63;
  const int wave = tid >> 6;      // 0..15
  const int wr   = wave >> 2;     // 0..3  row quarter
  const int wc   = wave & 3;      // 0..3  col quarter
  const int lm   = lane & 15;
  const int lk   = lane >> 4;
  const int bm   = blockIdx.x * BM;

  // A fragment source for (mi, kstep): row = bm+wr*64+mi*16+lm,
  // k = kstep*32 + lk*8 (8 consecutive fp32 = 2 fv4).
  const float* abase = act + (size_t)(bm + wr * 64 + lm) * NK + lk * 8;

  f32x4 acc[4][4] = {};
#pragma unroll
  for (int kk = 0; kk < 8; ++kk) {
    bf16x8 bfr[4];
#pragma unroll
    for (int ni = 0; ni < 4; ++ni)
      bfr[ni] = *(const bf16x8*)
          &Bs[(wc * 64 + ni * 16 + lm) * BST + kk * 32 + lk * 8];
#pragma unroll
    for (int mi = 0; mi < 4; ++mi) {
      const float* p = abase + (size_t)(mi * 16) * NK + kk * 32;
      const fv4 f0 = *(const fv4*)p;
      const fv4 f1 = *((const fv4*)p + 1);
      u32x4 apk;
      apk.x = pack_bf16(f0.x, f0.y); apk.y = pack_bf16(f0.z, f0.w);
      apk.z = pack_bf16(f1.x, f1.y); apk.w = pack_bf16(f1.z, f1.w);
      const bf16x8 af = __builtin_bit_cast(bf16x8, apk);
#pragma unroll
      for (int ni = 0; ni < 4; ++ni)
        acc[mi][ni] = __builtin_amdgcn_mfma_f32_16x16x32_bf16(
            af, bfr[ni], acc[mi][ni], 0, 0, 0);
    }
  }

  // Epilogue: abs-max + raw int32 store (cached -> LLC feeds pass 2).
  int imax = 0;
#pragma unroll
  for (int mi = 0; mi < 4; ++mi)
#pragma unroll
    for (int ni = 0; ni < 4; ++ni)
#pragma unroll
      for (int r = 0; r < 4; ++r) {
        const int ti = (int)acc[mi][ni][r];
        const int a = ti < 0 ? -ti : ti;
        imax = a > imax ? a : imax;
        const int m = bm + wr * 64 + mi * 16 + lk * 4 + r;
        const int n = wc * 64 + ni * 16 + lm;
        out[(size_t)m * NK + n] = ti;
      }
#pragma unroll
  for (int off = 32; off; off >>= 1) {
    const int o = __shfl_xor(imax, off, 64);
    imax = o > imax ? o : imax;
  }
  if (lane == 0) atomicMax(&smax, imax);
  __syncthreads();
  if (tid == 0) atomicMax(gmax, smax);
}

// pass 2: in-place elementwise quantize of d_out (raw temp is LLC-hot).
__global__ __launch_bounds__(256) void quant_pass(
    int* __restrict__ out, const int* __restrict__ gmax,
    const int* __restrict__ exp_in, const int* __restrict__ wexp)
{
  const int rmax = *gmax;
  const int bw = (rmax <= 1) ? 0 : (32 - __clz(rmax - 1));   // ceil(log2(r))
  const int shift = bw - 7;
  const bool pos = shift > 0;
  const int s = shift < 1 ? 1 : shift;

  const size_t total  = (size_t)M_ROWS * NK / 4;  // int4 vectors
  const size_t stride = (size_t)gridDim.x * blockDim.x;
  for (size_t i = (size_t)blockIdx.x * blockDim.x + threadIdx.x; i < total;
       i += stride) {
    iv4 t = ((const iv4*)out)[i];
    iv4 q;
#pragma unroll
    for (int j = 0; j < 4; ++j) {
      const int ti = t[j];
      int r;
      if (pos) {
        const int rt = ti >> s;                       // floor(t / 2^s)
        const int dec = (ti - (rt << s)) >> (s - 1);  // {0,1}
        r = rt + dec;
        r = r > 127 ? 127 : (r < -127 ? -127 : r);
      } else {
        r = (int)(signed char)(ti & 0xFF);            // int8 wrap
      }
      q[j] = r;
    }
    __builtin_nontemporal_store(q, &((iv4*)out)[i]); // final, never re-read
  }

  if (blockIdx.x == 0 && threadIdx.x == 0) {
    const int e = exp_in[0] + wexp[0] + (pos ? shift : 0);
    out[(size_t)M_ROWS * NK] = (int)(short)e;
  }
}

extern "C" void kernel_launch(void* const* d_in, const int* in_sizes, int n_in,
                              void* d_out, int out_size, void* d_ws, size_t ws_size,
                              hipStream_t stream) {
  const float* act   = (const float*)d_in[0];
  const int* exp_in  = (const int*)d_in[1];
  const float* wgt   = (const float*)d_in[2];
  const int* wexp    = (const int*)d_in[3];
  int* gmax          = (int*)d_ws;
  unsigned short* wb = (unsigned short*)((char*)d_ws + 128);  // 128 KB bf16 weight

  wconv<<<dim3(64), dim3(256), 0, stream>>>(wgt, wb, gmax);
  gemm_maxstore<<<dim3(M_ROWS / BM), dim3(1024), 0, stream>>>(act, wb, (int*)d_out,
                                                              gmax);
  quant_pass<<<dim3(2048), dim3(256), 0, stream>>>((int*)d_out, gmax, exp_in, wexp);
}

// Round 6
// 267.606 us; speedup vs baseline: 1.0955x; 1.0955x over previous
//
#include <hip/hip_runtime.h>
#include <stdint.h>

// B=131072 rows, K=IN=256, N=OUT=256.
// temp = act @ weight.T (exact int32, |t| < 2^22); r = max|temp|;
// bw = ceil(log2(max(r,1))) (0 if r<=1); shift = bw-7;
// shift>0 ? round_shift(temp,shift) clipped to [-127,127] : int8-wrap(temp)
// exp_out = exp_in + weight_exp + max(shift,0)  (int16 semantics)
// Harness reads d_out as INT32: [B*N values, 1 exp scalar].
//
// v7: int8 end-to-end (inputs are exactly int8-valued -> i8 MFMA is exact).
//  - Full B (256x256 i8, 68 KB padded) + A-tile (128x256 i8, 34 KB padded)
//    fit in LDS together -> K fully unrolled, no K-pipeline.
//  - k1: act fp32 read ONCE (134 MB), cvt->i8 in staging, act_i8 (33.5 MB)
//    written to d_ws for k2; GEMM -> global abs-max only. No raw temp.
//  - k2: recompute GEMM from act_i8 (LLC-hot), quantize in regs, single
//    final nt-store (134 MB). Raw int32 round-trip (402 MB) eliminated.
//  - d_ws >= 512 MB evidenced by harness 512 MiB poison fills.

#define M_ROWS 131072
#define NK 256
#define TM 128            // rows per A-tile
#define TILES 4           // A-tiles per block (512 rows/block, grid 256)
#define LSTR 272          // LDS row stride bytes (256 + 16 pad; ~2-way, proven)

typedef __attribute__((ext_vector_type(4))) int iv4;
typedef __attribute__((ext_vector_type(4))) float fv4;
typedef __attribute__((ext_vector_type(4))) unsigned int u32x4;

// D = A*B + C, 16x16 K=64, signed i8 inputs, i32 accum (exact).
// ISA form: v_mfma_i32_16x16x64_i8 D, A(4v), B(4v), C ; gfx950 unified file
// allows C/D in VGPRs.
__device__ __forceinline__ iv4 mfma_i8(iv4 a, iv4 b, iv4 c) {
  asm("v_mfma_i32_16x16x64_i8 %0, %1, %2, %0" : "+v"(c) : "v"(a), "v"(b));
  return c;
}

// 4 int-valued floats -> 4 packed signed bytes (two's complement).
__device__ __forceinline__ unsigned int pack_i8x4(float a, float b, float c,
                                                  float d) {
  return ((unsigned int)(int)a & 0xFFu) | (((unsigned int)(int)b & 0xFFu) << 8) |
         (((unsigned int)(int)c & 0xFFu) << 16) | ((unsigned int)(int)d << 24);
}

// Prepass: weight fp32 -> i8 (65536 elems, 64 KB out; L2/LLC-resident).
// Also zero-inits gmax.
__global__ void wconv(const float* __restrict__ w, unsigned char* __restrict__ wi8,
                      int* __restrict__ gmax) {
  if (blockIdx.x == 0 && threadIdx.x == 0) *gmax = 0;
  const int i = blockIdx.x * 256 + threadIdx.x;
  const fv4 f = ((const fv4*)w)[i];
  ((unsigned int*)wi8)[i] = pack_i8x4(f.x, f.y, f.z, f.w);
}

// k1: act fp32 -> i8 (stored to act8) + i8 GEMM -> global abs-max.
// 512 thr = 8 waves (2x4); wave (wr,wc) owns rows wr*64..+63, cols wc*64..+63
// of each 128x256 tile; acc iv4[4][4] (the proven non-spill shape).
__global__ __launch_bounds__(512, 1) void gemm_max_cvt(
    const float* __restrict__ act, const unsigned char* __restrict__ wi8,
    unsigned char* __restrict__ act8, int* __restrict__ gmax)
{
  __shared__ __align__(16) unsigned char As[TM * LSTR];   // 34816 B
  __shared__ __align__(16) unsigned char Bs[NK * LSTR];   // 69632 B
  __shared__ int smax;
  const int tid = threadIdx.x;
  if (tid == 0) smax = 0;

  // Stage full B once (wi8 row-major [col][k]).
  for (int c = tid; c < NK * NK / 16; c += 512) {
    const int col = c >> 4, kc = (c & 15) << 4;
    *(u32x4*)&Bs[col * LSTR + kc] = *(const u32x4*)(wi8 + col * NK + kc);
  }

  const int lane = tid & 63;
  const int wave = tid >> 6;      // 0..7
  const int wr   = wave >> 2;     // 0..1
  const int wc   = wave & 3;      // 0..3
  const int lm   = lane & 15;
  const int lk   = lane >> 4;

  int imax = 0;

  for (int t = 0; t < TILES; ++t) {
    const int tb = blockIdx.x * (TILES * TM) + t * TM;

    __syncthreads();   // protect As reuse (also covers Bs on t=0)
    // Stage A-tile: fp32 -> i8, also store i8 to global for k2.
#pragma unroll
    for (int j = 0; j < 4; ++j) {
      const int c   = j * 512 + tid;        // 0..2047 16B-chunks
      const int row = c >> 4;               // 0..127
      const int kc  = (c & 15) << 4;        // 0..240 (elem == byte)
      const float* p = act + (size_t)(tb + row) * NK + kc;
      const fv4 f0 = ((const fv4*)p)[0];
      const fv4 f1 = ((const fv4*)p)[1];
      const fv4 f2 = ((const fv4*)p)[2];
      const fv4 f3 = ((const fv4*)p)[3];
      u32x4 v;
      v.x = pack_i8x4(f0.x, f0.y, f0.z, f0.w);
      v.y = pack_i8x4(f1.x, f1.y, f1.z, f1.w);
      v.z = pack_i8x4(f2.x, f2.y, f2.z, f2.w);
      v.w = pack_i8x4(f3.x, f3.y, f3.z, f3.w);
      *(u32x4*)&As[row * LSTR + kc] = v;
      *(u32x4*)(act8 + (size_t)(tb + row) * NK + kc) = v;   // cached -> LLC
    }
    __syncthreads();

    iv4 acc[4][4] = {};
#pragma unroll
    for (int kk = 0; kk < 4; ++kk) {        // K = 4 x 64
      iv4 af[4], bf[4];
#pragma unroll
      for (int mi = 0; mi < 4; ++mi)
        af[mi] = *(const iv4*)&As[(wr * 64 + mi * 16 + lm) * LSTR + kk * 64 + lk * 16];
#pragma unroll
      for (int ni = 0; ni < 4; ++ni)
        bf[ni] = *(const iv4*)&Bs[(wc * 64 + ni * 16 + lm) * LSTR + kk * 64 + lk * 16];
#pragma unroll
      for (int mi = 0; mi < 4; ++mi)
#pragma unroll
        for (int ni = 0; ni < 4; ++ni)
          acc[mi][ni] = mfma_i8(af[mi], bf[ni], acc[mi][ni]);
    }

#pragma unroll
    for (int mi = 0; mi < 4; ++mi)
#pragma unroll
      for (int ni = 0; ni < 4; ++ni)
#pragma unroll
        for (int r = 0; r < 4; ++r) {
          const int ti = acc[mi][ni][r];
          const int a = ti < 0 ? -ti : ti;
          imax = a > imax ? a : imax;
        }
  }

#pragma unroll
  for (int off = 32; off; off >>= 1) {
    const int o = __shfl_xor(imax, off, 64);
    imax = o > imax ? o : imax;
  }
  if (lane == 0) atomicMax(&smax, imax);
  __syncthreads();
  if (tid == 0) atomicMax(gmax, smax);
}

// k2: i8 GEMM from act8 (LLC-hot) -> quantize in regs -> final nt-store.
__global__ __launch_bounds__(512, 1) void gemm_quant(
    const unsigned char* __restrict__ act8, const unsigned char* __restrict__ wi8,
    int* __restrict__ out, const int* __restrict__ gmax,
    const int* __restrict__ exp_in, const int* __restrict__ wexp)
{
  __shared__ __align__(16) unsigned char As[TM * LSTR];
  __shared__ __align__(16) unsigned char Bs[NK * LSTR];

  const int rmax = *gmax;
  const int bw = (rmax <= 1) ? 0 : (32 - __clz(rmax - 1));   // ceil(log2(r))
  const int shift = bw - 7;
  const bool pos = shift > 0;
  const int s = shift < 1 ? 1 : shift;

  const int tid = threadIdx.x;
  for (int c = tid; c < NK * NK / 16; c += 512) {
    const int col = c >> 4, kc = (c & 15) << 4;
    *(u32x4*)&Bs[col * LSTR + kc] = *(const u32x4*)(wi8 + col * NK + kc);
  }

  const int lane = tid & 63;
  const int wave = tid >> 6;
  const int wr   = wave >> 2;
  const int wc   = wave & 3;
  const int lm   = lane & 15;
  const int lk   = lane >> 4;

  for (int t = 0; t < TILES; ++t) {
    const int tb = blockIdx.x * (TILES * TM) + t * TM;

    __syncthreads();
#pragma unroll
    for (int j = 0; j < 4; ++j) {
      const int c   = j * 512 + tid;
      const int row = c >> 4;
      const int kc  = (c & 15) << 4;
      *(u32x4*)&As[row * LSTR + kc] =
          *(const u32x4*)(act8 + (size_t)(tb + row) * NK + kc);
    }
    __syncthreads();

    iv4 acc[4][4] = {};
#pragma unroll
    for (int kk = 0; kk < 4; ++kk) {
      iv4 af[4], bf[4];
#pragma unroll
      for (int mi = 0; mi < 4; ++mi)
        af[mi] = *(const iv4*)&As[(wr * 64 + mi * 16 + lm) * LSTR + kk * 64 + lk * 16];
#pragma unroll
      for (int ni = 0; ni < 4; ++ni)
        bf[ni] = *(const iv4*)&Bs[(wc * 64 + ni * 16 + lm) * LSTR + kk * 64 + lk * 16];
#pragma unroll
      for (int mi = 0; mi < 4; ++mi)
#pragma unroll
        for (int ni = 0; ni < 4; ++ni)
          acc[mi][ni] = mfma_i8(af[mi], bf[ni], acc[mi][ni]);
    }

    // Quantize + final store (nt: never re-read).
#pragma unroll
    for (int mi = 0; mi < 4; ++mi)
#pragma unroll
      for (int ni = 0; ni < 4; ++ni)
#pragma unroll
        for (int r = 0; r < 4; ++r) {
          const int ti = acc[mi][ni][r];
          int q;
          if (pos) {
            const int rt = ti >> s;                       // floor(t / 2^s)
            const int dec = (ti - (rt << s)) >> (s - 1);  // {0,1}
            q = rt + dec;
            q = q > 127 ? 127 : (q < -127 ? -127 : q);
          } else {
            q = (int)(signed char)(ti & 0xFF);            // int8 wrap
          }
          const int m = tb + wr * 64 + mi * 16 + lk * 4 + r;
          const int n = wc * 64 + ni * 16 + lm;
          __builtin_nontemporal_store(q, &out[(size_t)m * NK + n]);
        }
  }

  if (blockIdx.x == 0 && tid == 0) {
    const int e = exp_in[0] + wexp[0] + (pos ? shift : 0);
    out[(size_t)M_ROWS * NK] = (int)(short)e;
  }
}

extern "C" void kernel_launch(void* const* d_in, const int* in_sizes, int n_in,
                              void* d_out, int out_size, void* d_ws, size_t ws_size,
                              hipStream_t stream) {
  const float* act   = (const float*)d_in[0];
  const int* exp_in  = (const int*)d_in[1];
  const float* wgt   = (const float*)d_in[2];
  const int* wexp    = (const int*)d_in[3];
  int* gmax           = (int*)d_ws;
  unsigned char* wi8  = (unsigned char*)d_ws + 4096;        // 64 KB
  unsigned char* act8 = (unsigned char*)d_ws + (1 << 20);   // 33.5 MB

  wconv<<<dim3(64), dim3(256), 0, stream>>>(wgt, wi8, gmax);
  gemm_max_cvt<<<dim3(M_ROWS / (TILES * TM)), dim3(512), 0, stream>>>(
      act, wi8, act8, gmax);
  gemm_quant<<<dim3(M_ROWS / (TILES * TM)), dim3(512), 0, stream>>>(
      act8, wi8, (int*)d_out, gmax, exp_in, wexp);
}